// Round 11
// baseline (787.749 us; speedup 1.0000x reference)
//
#include <hip/hip_runtime.h>
#include <hip/hip_cooperative_groups.h>
#include <cfloat>

namespace cg = cooperative_groups;

#define HID 240

static inline size_t alignUp(size_t x, size_t a){ return (x + a - 1) / a * a; }

typedef __bf16 bf16x8 __attribute__((ext_vector_type(8)));
typedef unsigned short u16x8 __attribute__((ext_vector_type(8)));
typedef float  f32x16 __attribute__((ext_vector_type(16)));

__device__ __forceinline__ float b2f(unsigned short u){
    return __uint_as_float(((unsigned)u) << 16);
}
__device__ __forceinline__ unsigned short f2b_rne(float f){
    unsigned r = __float_as_uint(f);
    r += 0x7FFFu + ((r >> 16) & 1u);
    return (unsigned short)(r >> 16);
}

// ================ cooperative build: all graph prep in ONE kernel ================
// phases: 0 zero pk | 1 deg_hist(+rank) + weight/x prep | 2 dis/cnt/bsum |
//         3 scan bsum (block 0) | 4 offs+fill | 5 atomic-free scatter
__global__ void k_build(const int* __restrict__ col, const float* __restrict__ ew,
                        const int* __restrict__ row,
                        unsigned long long* __restrict__ pk, unsigned* __restrict__ rank,
                        float* __restrict__ dis, unsigned* __restrict__ cnt,
                        unsigned* __restrict__ bsum, unsigned* __restrict__ boff,
                        unsigned* __restrict__ poff, int2* __restrict__ sedge,
                        const float* __restrict__ x, float* __restrict__ xp,
                        const float* __restrict__ W1, unsigned short* __restrict__ W1f,
                        const float* __restrict__ W2, unsigned short* __restrict__ Bt2h,
                        unsigned short* __restrict__ Bt2l,
                        const float* __restrict__ We, unsigned short* __restrict__ Bt3h,
                        unsigned short* __restrict__ Bt3l,
                        int N, int E, int nb){
    cg::grid_group grid = cg::this_grid();
    __shared__ unsigned ws[4];
    int t = threadIdx.x;
    int lane = t & 63, w = t >> 6;
    int gtid = blockIdx.x * 256 + t;
    int gsz  = gridDim.x * 256;

    // ---- phase 0: zero pk ----
    for (int i = gtid; i < N; i += gsz) pk[i] = 0ull;
    grid.sync();

    // ---- phase 1: degree histogram (packed 64-bit atomic) + rank ----
    for (int e = gtid; e < E; e += gsz){
        int c = col[e];
        unsigned q = __float2uint_rn(ew[e] * 1048576.0f);
        unsigned long long old = atomicAdd(&pk[c], (1ull << 40) | (unsigned long long)q);
        rank[e] = (unsigned)(old >> 40);
    }
    // ---- phase 1b (overlapped): xp pad + weight splits ----
    for (int i = gtid; i < N; i += gsz){
        const float* xr = x + (size_t)i * 5;
        float v0 = xr[0], v1 = xr[1], v2 = xr[2], v3 = xr[3], v4 = xr[4];
        float* o = xp + (size_t)i * 8;
        o[0] = v0; o[1] = v1; o[2] = v2; o[3] = v3;
        o[4] = v4; o[5] = 0.f; o[6] = 0.f; o[7] = 0.f;
    }
    for (int i = gtid; i < 2 * 8 * 64 * 8; i += gsz){
        int k    = i & 7;
        int ln   = (i >> 3) & 63;
        int j    = (i >> 9) & 7;
        int s2   = i >> 12;
        int lm = ln & 31, quad = ln >> 5;
        int kg = quad * 8 + k;
        int colm = 32 * j + lm;
        float v = (kg < 5 && colm < HID) ? W1[kg * HID + colm] : 0.0f;
        unsigned short hi = f2b_rne(v);
        W1f[i] = (s2 == 0) ? hi : f2b_rne(v - b2f(hi));
    }
    for (int i = gtid; i < 256 * HID; i += gsz){
        int n = i / HID, k = i - n * HID;
        float v = (n < HID) ? W2[(size_t)k * HID + n] : 0.0f;
        unsigned short hi = f2b_rne(v);
        Bt2h[i] = hi;
        Bt2l[i] = f2b_rne(v - b2f(hi));
    }
    for (int i = gtid; i < 128 * HID; i += gsz){
        int n = i / HID, k = i - n * HID;
        float v = (n < 80) ? We[(size_t)k * 80 + n] : 0.0f;
        unsigned short hi = f2b_rne(v);
        Bt3h[i] = hi;
        Bt3l[i] = f2b_rne(v - b2f(hi));
    }
    grid.sync();

    // ---- phase 2: unpack pk -> dis,cnt; per-segment chunk sums ----
    for (int seg = blockIdx.x; seg < nb; seg += gridDim.x){
        int i = seg * 256 + t;
        unsigned v = 0u;
        if (i < N){
            unsigned long long p = pk[i];
            unsigned c = (unsigned)(p >> 40);
            cnt[i] = c;
            float deg = 1.0f + (float)(p & 0xFFFFFFFFFFull) * (1.0f / 1048576.0f);
            dis[i] = rsqrtf(deg);
            v = (c + 32u) >> 5;
        }
        unsigned r = v;
        #pragma unroll
        for (int o = 32; o > 0; o >>= 1) r += __shfl_down(r, (unsigned)o, 64);
        if (lane == 0) ws[w] = r;
        __syncthreads();
        if (t == 0) bsum[seg] = ws[0] + ws[1] + ws[2] + ws[3];
        __syncthreads();
    }
    grid.sync();

    // ---- phase 3: exclusive scan of bsum (block 0, one wave) ----
    if (blockIdx.x == 0 && t < 64){
        unsigned carry = 0u;
        for (int base = 0; base < nb; base += 64){
            int i = base + lane;
            unsigned v = (i < nb) ? bsum[i] : 0u;
            unsigned xacc = v;
            #pragma unroll
            for (int o = 1; o < 64; o <<= 1){
                unsigned u = __shfl_up(xacc, (unsigned)o, 64);
                if (lane >= o) xacc += u;
            }
            if (i < nb) boff[i] = carry + xacc - v;
            carry += __shfl(xacc, 63, 64);
        }
        if (lane == 0) poff[N] = 32u * carry;
    }
    grid.sync();

    // ---- phase 4: padded offsets + self-slot/tail fill ----
    for (int seg = blockIdx.x; seg < nb; seg += gridDim.x){
        int i = seg * 256 + t;
        unsigned c = (i < N) ? cnt[i] : 0u;
        unsigned v = (i < N) ? ((c + 32u) >> 5) : 0u;
        unsigned xacc = v;
        #pragma unroll
        for (int o = 1; o < 64; o <<= 1){
            unsigned u = __shfl_up(xacc, (unsigned)o, 64);
            if (lane >= o) xacc += u;
        }
        if (lane == 63) ws[w] = xacc;
        __syncthreads();
        unsigned wb = 0;
        if (w > 0) wb += ws[0];
        if (w > 1) wb += ws[1];
        if (w > 2) wb += ws[2];
        if (i < N){
            unsigned p = 32u * (boff[seg] + wb + xacc - v);
            poff[i] = p;
            float dd = dis[i];
            int2 sv = make_int2(i, __float_as_int(dd * dd));
            sedge[p] = sv;
            unsigned s1 = p + 32u * v;
            for (unsigned s = p + 1u + c; s < s1; s++) sedge[s] = sv;
        }
        __syncthreads();
    }
    grid.sync();

    // ---- phase 5: atomic-free scatter ----
    for (int e = gtid; e < E; e += gsz){
        int r = row[e], c = col[e];
        float nw = dis[r] * ew[e] * dis[c];
        unsigned p = poff[c] + 1u + rank[e];
        sedge[p] = make_int2(r, __float_as_int(nw));
    }
}

// ---------------- layer-1 fused linear+max-agg via MFMA ----------------
__global__ __launch_bounds__(256) void k_agg1m(const float* __restrict__ xp,
                                               const unsigned short* __restrict__ W1f,
                                               const unsigned* __restrict__ cnt,
                                               const unsigned* __restrict__ poff,
                                               const int2* __restrict__ sedge,
                                               const float* __restrict__ bias,
                                               float* __restrict__ out, int N, int nwaves){
    int wid  = blockIdx.x * 4 + (threadIdx.x >> 6);
    int lane = threadIdx.x & 63;
    int lm   = lane & 31;

    bf16x8 bh[8], bl[8];
    #pragma unroll
    for (int j = 0; j < 8; j++){
        bh[j] = *(const bf16x8*)(W1f + ((size_t)(0 * 8 + j) * 64 + lane) * 8);
        bl[j] = *(const bf16x8*)(W1f + ((size_t)(1 * 8 + j) * 64 + lane) * 8);
    }
    float bv[8];
    #pragma unroll
    for (int j = 0; j < 8; j++){
        int c = 32 * j + lm;
        bv[j] = (c < HID) ? bias[c] : 0.0f;
    }
    const f32x16 zv = {};

    for (int d = wid; d < N; d += nwaves){
        unsigned base = poff[d];
        unsigned nch  = (cnt[d] + 32u) >> 5;
        float m[8];
        #pragma unroll
        for (int j = 0; j < 8; j++) m[j] = -FLT_MAX;

        for (unsigned c = 0; c < nch; c++){
            u16x8 ahu = (u16x8)0, alu = (u16x8)0;
            if (lane < 32){
                int2 e = sedge[base + 32u * c + (unsigned)lm];
                float w = __int_as_float(e.y);
                const float4* xr = (const float4*)(xp + (size_t)e.x * 8);
                float4 x0 = xr[0], x1 = xr[1];
                float p[5] = {w * x0.x, w * x0.y, w * x0.z, w * x0.w, w * x1.x};
                #pragma unroll
                for (int k = 0; k < 5; k++){
                    unsigned short h = f2b_rne(p[k]);
                    ahu[k] = h;
                    alu[k] = f2b_rne(p[k] - b2f(h));
                }
            }
            bf16x8 ah = __builtin_bit_cast(bf16x8, ahu);
            bf16x8 al = __builtin_bit_cast(bf16x8, alu);
            #pragma unroll
            for (int j = 0; j < 8; j += 2){
                f32x16 a0 = __builtin_amdgcn_mfma_f32_32x32x16_bf16(ah, bh[j],     zv, 0, 0, 0);
                f32x16 a1 = __builtin_amdgcn_mfma_f32_32x32x16_bf16(ah, bh[j + 1], zv, 0, 0, 0);
                a0 = __builtin_amdgcn_mfma_f32_32x32x16_bf16(ah, bl[j],     a0, 0, 0, 0);
                a1 = __builtin_amdgcn_mfma_f32_32x32x16_bf16(ah, bl[j + 1], a1, 0, 0, 0);
                a0 = __builtin_amdgcn_mfma_f32_32x32x16_bf16(al, bh[j],     a0, 0, 0, 0);
                a1 = __builtin_amdgcn_mfma_f32_32x32x16_bf16(al, bh[j + 1], a1, 0, 0, 0);
                #pragma unroll
                for (int r = 0; r < 16; r++){
                    m[j]     = fmaxf(m[j],     a0[r]);
                    m[j + 1] = fmaxf(m[j + 1], a1[r]);
                }
            }
        }
        float o[8];
        #pragma unroll
        for (int j = 0; j < 8; j++){
            float other = __shfl_xor(m[j], 32, 64);
            o[j] = fmaxf(fmaxf(m[j], other) + bv[j], 0.0f);
        }
        if (lane < 32){
            float* orow = out + (size_t)d * HID;
            #pragma unroll
            for (int j = 0; j < 8; j++){
                int c = 32 * j + lm;
                if (c < HID) orow[c] = o[j];
            }
        }
    }
}

// ---------------- split-bf16 MFMA GEMM: C = A(M x 240) @ W(240 x Ncol) ----------------
template <bool OB16>
__global__ __launch_bounds__(256) void k_gemm_mfma(const float* __restrict__ A,
                                                   const unsigned short* __restrict__ Bth,
                                                   const unsigned short* __restrict__ Btl,
                                                   const float* __restrict__ bias,
                                                   void* __restrict__ Cv,
                                                   int M, int Ncol, int Npad){
    __shared__ unsigned short As_hi[32][24];
    __shared__ unsigned short As_lo[32][24];
    const int K = 240;
    int t = threadIdx.x;
    int wave = t >> 6, lane = t & 63;
    int m0 = blockIdx.x * 32;
    int n0 = wave * 64;
    bool wact = n0 < Npad;

    int lm   = lane & 31;
    int quad = lane >> 5;

    f32x16 acc0 = {};
    f32x16 acc1 = {};

    for (int k0 = 0; k0 < K; k0 += 16){
        if (t < 128){
            int m = t >> 2, kq = (t & 3) * 4;
            float4 av = make_float4(0.f, 0.f, 0.f, 0.f);
            if (m0 + m < M) av = *(const float4*)(A + (size_t)(m0 + m) * K + k0 + kq);
            ushort4 hi, lo;
            hi.x = f2b_rne(av.x); lo.x = f2b_rne(av.x - b2f(hi.x));
            hi.y = f2b_rne(av.y); lo.y = f2b_rne(av.y - b2f(hi.y));
            hi.z = f2b_rne(av.z); lo.z = f2b_rne(av.z - b2f(hi.z));
            hi.w = f2b_rne(av.w); lo.w = f2b_rne(av.w - b2f(hi.w));
            *(ushort4*)&As_hi[m][kq] = hi;
            *(ushort4*)&As_lo[m][kq] = lo;
        }
        __syncthreads();
        if (wact){
            bf16x8 ah = *(const bf16x8*)&As_hi[lm][quad * 8];
            bf16x8 al = *(const bf16x8*)&As_lo[lm][quad * 8];
            size_t bo0 = (size_t)(n0 + lm) * K + k0 + quad * 8;
            size_t bo1 = (size_t)(n0 + 32 + lm) * K + k0 + quad * 8;
            bf16x8 bh0 = *(const bf16x8*)(Bth + bo0);
            bf16x8 bl0 = *(const bf16x8*)(Btl + bo0);
            bf16x8 bh1 = *(const bf16x8*)(Bth + bo1);
            bf16x8 bl1 = *(const bf16x8*)(Btl + bo1);
            acc0 = __builtin_amdgcn_mfma_f32_32x32x16_bf16(ah, bh0, acc0, 0, 0, 0);
            acc0 = __builtin_amdgcn_mfma_f32_32x32x16_bf16(ah, bl0, acc0, 0, 0, 0);
            acc0 = __builtin_amdgcn_mfma_f32_32x32x16_bf16(al, bh0, acc0, 0, 0, 0);
            acc1 = __builtin_amdgcn_mfma_f32_32x32x16_bf16(ah, bh1, acc1, 0, 0, 0);
            acc1 = __builtin_amdgcn_mfma_f32_32x32x16_bf16(ah, bl1, acc1, 0, 0, 0);
            acc1 = __builtin_amdgcn_mfma_f32_32x32x16_bf16(al, bh1, acc1, 0, 0, 0);
        }
        __syncthreads();
    }

    if (!wact) return;
    #pragma unroll
    for (int h = 0; h < 2; h++){
        int n = n0 + 32 * h + lm;
        if (n >= Ncol) continue;
        float bvv = (!OB16 && bias) ? bias[n] : 0.0f;
        #pragma unroll
        for (int r = 0; r < 16; r++){
            int m = m0 + (r & 3) + 8 * (r >> 2) + 4 * quad;
            if (m >= M) continue;
            float v = (h == 0) ? acc0[r] : acc1[r];
            if (OB16){
                ((unsigned short*)Cv)[(size_t)m * Ncol + n] = f2b_rne(v);
            } else {
                ((float*)Cv)[(size_t)m * Ncol + n] = v + bvv;
            }
        }
    }
}

// ---------------- layer-2 scatter-max over bf16 rows (self slot included), +bias, ReLU ----------------
__global__ __launch_bounds__(256) void k_aggb(const unsigned short* __restrict__ H2,
                                              const unsigned* __restrict__ cnt,
                                              const unsigned* __restrict__ poff,
                                              const int2* __restrict__ sedge,
                                              const float* __restrict__ bias,
                                              float* __restrict__ out, int N){
    int d    = blockIdx.x * 4 + (threadIdx.x >> 6);
    int lane = threadIdx.x & 63;
    if (d >= N) return;
    bool act = lane < 60;

    float4 m = make_float4(-FLT_MAX, -FLT_MAX, -FLT_MAX, -FLT_MAX);
    unsigned p0 = poff[d], p1 = p0 + 1u + cnt[d];
    unsigned p = p0;
    for (; p + 4 <= p1; p += 4){
        int2 e0 = sedge[p], e1 = sedge[p+1], e2 = sedge[p+2], e3 = sedge[p+3];
        if (act){
            ushort4 g0 = ((const ushort4*)(H2 + (size_t)e0.x * HID))[lane];
            ushort4 g1 = ((const ushort4*)(H2 + (size_t)e1.x * HID))[lane];
            ushort4 g2 = ((const ushort4*)(H2 + (size_t)e2.x * HID))[lane];
            ushort4 g3 = ((const ushort4*)(H2 + (size_t)e3.x * HID))[lane];
            float w0 = __int_as_float(e0.y), w1 = __int_as_float(e1.y);
            float w2 = __int_as_float(e2.y), w3 = __int_as_float(e3.y);
            m.x = fmaxf(fmaxf(m.x, w0*b2f(g0.x)), fmaxf(w1*b2f(g1.x), fmaxf(w2*b2f(g2.x), w3*b2f(g3.x))));
            m.y = fmaxf(fmaxf(m.y, w0*b2f(g0.y)), fmaxf(w1*b2f(g1.y), fmaxf(w2*b2f(g2.y), w3*b2f(g3.y))));
            m.z = fmaxf(fmaxf(m.z, w0*b2f(g0.z)), fmaxf(w1*b2f(g1.z), fmaxf(w2*b2f(g2.z), w3*b2f(g3.z))));
            m.w = fmaxf(fmaxf(m.w, w0*b2f(g0.w)), fmaxf(w1*b2f(g1.w), fmaxf(w2*b2f(g2.w), w3*b2f(g3.w))));
        }
    }
    for (; p < p1; p++){
        int2 e0 = sedge[p];
        if (act){
            ushort4 g0 = ((const ushort4*)(H2 + (size_t)e0.x * HID))[lane];
            float w0 = __int_as_float(e0.y);
            m.x = fmaxf(m.x, w0 * b2f(g0.x)); m.y = fmaxf(m.y, w0 * b2f(g0.y));
            m.z = fmaxf(m.z, w0 * b2f(g0.z)); m.w = fmaxf(m.w, w0 * b2f(g0.w));
        }
    }
    if (act){
        float4 b = ((const float4*)bias)[lane];
        float4 o;
        o.x = fmaxf(m.x + b.x, 0.0f);
        o.y = fmaxf(m.y + b.y, 0.0f);
        o.z = fmaxf(m.z + b.z, 0.0f);
        o.w = fmaxf(m.w + b.w, 0.0f);
        ((float4*)(out + (size_t)d * HID))[lane] = o;
    }
}

extern "C" void kernel_launch(void* const* d_in, const int* in_sizes, int n_in,
                              void* d_out, int out_size, void* d_ws, size_t ws_size,
                              hipStream_t stream){
    const float* x  = (const float*)d_in[0];
    const int*   ei = (const int*)  d_in[1];
    const float* ew = (const float*)d_in[2];
    const float* W1 = (const float*)d_in[3];
    const float* b1 = (const float*)d_in[4];
    const float* W2 = (const float*)d_in[5];
    const float* b2 = (const float*)d_in[6];
    const float* We = (const float*)d_in[7];
    const float* be = (const float*)d_in[8];
    float* out = (float*)d_out;

    const int N = in_sizes[0] / 5;
    const int E = in_sizes[2];
    const int* row = ei;
    const int* col = ei + E;
    const int nb = (N + 255) / 256;

    char* w = (char*)d_ws;
    size_t o = 0;
    auto alloc = [&](size_t bytes) -> void* {
        void* p = w + o;
        o = alignUp(o + bytes, 256);
        return p;
    };
    unsigned long long* pk = (unsigned long long*) alloc((size_t)N * 8);
    float*          dis   = (float*)          alloc((size_t)N * 4);
    unsigned*       cnt   = (unsigned*)       alloc((size_t)N * 4);
    unsigned*       poff  = (unsigned*)       alloc((size_t)(N + 1) * 4);
    unsigned*       bsum  = (unsigned*)       alloc((size_t)nb * 4);
    unsigned*       boff  = (unsigned*)       alloc((size_t)nb * 4);
    unsigned*       rank  = (unsigned*)       alloc((size_t)E * 4);
    int2*           sedge = (int2*)           alloc(((size_t)E + 32u * N + 64u) * 8);
    float*          xp    = (float*)          alloc((size_t)N * 8 * 4);
    unsigned short* W1f   = (unsigned short*) alloc((size_t)2 * 8 * 64 * 8 * 2);
    unsigned short* Bt2h  = (unsigned short*) alloc((size_t)256 * HID * 2);
    unsigned short* Bt2l  = (unsigned short*) alloc((size_t)256 * HID * 2);
    unsigned short* Bt3h  = (unsigned short*) alloc((size_t)128 * HID * 2);
    unsigned short* Bt3l  = (unsigned short*) alloc((size_t)128 * HID * 2);
    unsigned short* bufH2 = (unsigned short*) alloc((size_t)N * HID * 2);
    float*          bufB  = (float*)          alloc((size_t)N * HID * 4);
    (void)ws_size; (void)n_in; (void)out_size;

    // ---- cooperative build: whole graph-prep chain in one launch ----
    {
        void* args[] = {
            (void*)&col, (void*)&ew, (void*)&row,
            (void*)&pk, (void*)&rank, (void*)&dis, (void*)&cnt,
            (void*)&bsum, (void*)&boff, (void*)&poff, (void*)&sedge,
            (void*)&x, (void*)&xp,
            (void*)&W1, (void*)&W1f,
            (void*)&W2, (void*)&Bt2h, (void*)&Bt2l,
            (void*)&We, (void*)&Bt3h, (void*)&Bt3l,
            (void*)&N, (void*)&E, (void*)&nb
        };
        hipLaunchCooperativeKernel((void*)k_build, dim3(512), dim3(256), args, 0, stream);
    }

    // layer 1: MFMA fused linear + max-agg + b1 + ReLU
    const int a1blocks = 768;
    k_agg1m<<<a1blocks, 256, 0, stream>>>(xp, W1f, cnt, poff, sedge, b1, bufB, N, a1blocks * 4);

    // layer 2: split-bf16 MFMA GEMM -> bf16 rows, then bf16-gather max-agg + b2 + ReLU
    int gm = (N + 31) / 32;
    k_gemm_mfma<true><<<gm, 256, 0, stream>>>(bufB, Bt2h, Bt2l, nullptr, bufH2, N, HID, 256);
    k_aggb<<<(N + 3) / 4, 256, 0, stream>>>(bufH2, cnt, poff, sedge, b2, bufB, N);

    // readout: split-bf16 MFMA GEMM -> fp32 out + be
    k_gemm_mfma<false><<<gm, 256, 0, stream>>>(bufB, Bt3h, Bt3l, be, out, N, 80, 128);
}

// Round 12
// 512.351 us; speedup vs baseline: 1.5375x; 1.5375x over previous
//
#include <hip/hip_runtime.h>
#include <cfloat>

#define HID 240

static inline size_t alignUp(size_t x, size_t a){ return (x + a - 1) / a * a; }

typedef __bf16 bf16x8 __attribute__((ext_vector_type(8)));
typedef unsigned short u16x8 __attribute__((ext_vector_type(8)));
typedef float  f32x16 __attribute__((ext_vector_type(16)));

__device__ __forceinline__ float b2f(unsigned short u){
    return __uint_as_float(((unsigned)u) << 16);
}
__device__ __forceinline__ unsigned short f2b_rne(float f){
    unsigned r = __float_as_uint(f);
    r += 0x7FFFu + ((r >> 16) & 1u);
    return (unsigned short)(r >> 16);
}

// ---------------- degree + count in ONE 64-bit atomic per edge; rank = old cnt ----------------
// bits [0,40): sum of round(ew * 2^20); bits [40,64): edge count
__global__ void k_deg_hist(const int* __restrict__ col, const float* __restrict__ ew,
                           unsigned long long* __restrict__ pk,
                           unsigned* __restrict__ rank, int E){
    int e = blockIdx.x * blockDim.x + threadIdx.x;
    if (e < E){
        int c = col[e];
        unsigned q = __float2uint_rn(ew[e] * 1048576.0f);
        unsigned long long old = atomicAdd(&pk[c], (1ull << 40) | (unsigned long long)q);
        rank[e] = (unsigned)(old >> 40);
    }
}

// ---------------- unpack pk -> dis,cnt + bsum  |  fused prep (disjoint block ranges) ----------------
// blocks [0,nb): dis/cnt/bsum; [nb,2nb): xp pad; then W1 frags, W2 split, We split.
__global__ void k_dis_prep(const unsigned long long* __restrict__ pk,
                           float* __restrict__ dis, unsigned* __restrict__ cnt,
                           unsigned* __restrict__ bsum, int N, int nb,
                           const float* __restrict__ x, float* __restrict__ xp,
                           const float* __restrict__ W1, unsigned short* __restrict__ W1f,
                           const float* __restrict__ W2, unsigned short* __restrict__ Bt2h,
                           unsigned short* __restrict__ Bt2l,
                           const float* __restrict__ We, unsigned short* __restrict__ Bt3h,
                           unsigned short* __restrict__ Bt3l){
    int b = blockIdx.x;
    int t = threadIdx.x;
    if (b < nb){
        int i = b * 256 + t;
        unsigned v = 0u;
        if (i < N){
            unsigned long long p = pk[i];
            unsigned c = (unsigned)(p >> 40);
            cnt[i] = c;
            float deg = 1.0f + (float)(p & 0xFFFFFFFFFFull) * (1.0f / 1048576.0f);
            dis[i] = rsqrtf(deg);
            v = (c + 32u) >> 5;
        }
        #pragma unroll
        for (int o = 32; o > 0; o >>= 1) v += __shfl_down(v, (unsigned)o, 64);
        __shared__ unsigned ws[4];
        int lane = t & 63, w = t >> 6;
        if (lane == 0) ws[w] = v;
        __syncthreads();
        if (t == 0) bsum[b] = ws[0] + ws[1] + ws[2] + ws[3];
        return;
    }
    int bb = b - nb;
    if (bb < nb){
        __shared__ float s[1280];
        int rbase = bb * 256;
        #pragma unroll
        for (int c = 0; c < 5; c++){
            int idx = rbase * 5 + t + 256 * c;
            s[t + 256 * c] = (idx < N * 5) ? x[idx] : 0.0f;
        }
        __syncthreads();
        #pragma unroll
        for (int c = 0; c < 8; c++){
            int pos = t + 256 * c;
            int r = pos >> 3, j = pos & 7;
            int grow = rbase + r;
            if (grow < N)
                xp[(size_t)grow * 8 + j] = (j < 5) ? s[r * 5 + j] : 0.0f;
        }
        return;
    }
    bb -= nb;
    if (bb < 32){
        int i = bb * 256 + t;
        if (i < 2 * 8 * 64 * 8){
            int k    = i & 7;
            int lane = (i >> 3) & 63;
            int j    = (i >> 9) & 7;
            int s2   = i >> 12;
            int lm = lane & 31, quad = lane >> 5;
            int kg = quad * 8 + k;
            int colm = 32 * j + lm;
            float v = (kg < 5 && colm < HID) ? W1[kg * HID + colm] : 0.0f;
            unsigned short hi = f2b_rne(v);
            W1f[i] = (s2 == 0) ? hi : f2b_rne(v - b2f(hi));
        }
        return;
    }
    bb -= 32;
    if (bb < 240){
        int i = bb * 256 + t;
        int n = i / HID, k = i - n * HID;
        float v = (n < HID) ? W2[(size_t)k * HID + n] : 0.0f;
        unsigned short hi = f2b_rne(v);
        Bt2h[i] = hi;
        Bt2l[i] = f2b_rne(v - b2f(hi));
        return;
    }
    bb -= 240;
    {
        int i = bb * 256 + t;
        if (i < 128 * HID){
            int n = i / HID, k = i - n * HID;
            float v = (n < 80) ? We[(size_t)k * 80 + n] : 0.0f;
            unsigned short hi = f2b_rne(v);
            Bt3h[i] = hi;
            Bt3l[i] = f2b_rne(v - b2f(hi));
        }
    }
}

// ---------------- scan of block sums (nb <= 256); also writes poff[N] ----------------
__global__ void k_bscan(const unsigned* __restrict__ bsum, unsigned* __restrict__ boff,
                        unsigned* __restrict__ poff, int nb, int N){
    __shared__ unsigned s[256];
    int t = threadIdx.x;
    unsigned v = (t < nb) ? bsum[t] : 0u;
    s[t] = v;
    __syncthreads();
    for (int o = 1; o < 256; o <<= 1){
        unsigned u = (t >= o) ? s[t - o] : 0u;
        __syncthreads();
        s[t] += u;
        __syncthreads();
    }
    if (t < nb) boff[t] = s[t] - v;
    if (t == 0) poff[N] = 32u * s[nb - 1];
}

// ---------------- offsets + self-slot/tail fill ----------------
__global__ void k_offs_fill(const unsigned* __restrict__ cnt, const unsigned* __restrict__ boff,
                            const float* __restrict__ dis,
                            unsigned* __restrict__ poff, int2* __restrict__ sedge, int N){
    int b = blockIdx.x, t = threadIdx.x;
    int i = b * 256 + t;
    unsigned c = (i < N) ? cnt[i] : 0u;
    unsigned v = (i < N) ? ((c + 32u) >> 5) : 0u;
    int lane = t & 63, w = t >> 6;
    unsigned x = v;
    #pragma unroll
    for (int o = 1; o < 64; o <<= 1){
        unsigned u = __shfl_up(x, (unsigned)o, 64);
        if (lane >= o) x += u;
    }
    __shared__ unsigned ws[4];
    if (lane == 63) ws[w] = x;
    __syncthreads();
    unsigned wb = 0;
    if (w > 0) wb += ws[0];
    if (w > 1) wb += ws[1];
    if (w > 2) wb += ws[2];
    if (i < N){
        unsigned p = 32u * (boff[b] + wb + x - v);
        poff[i] = p;
        float dd = dis[i];
        int2 sv = make_int2(i, __float_as_int(dd * dd));
        sedge[p] = sv;
        unsigned s1 = p + 32u * v;
        for (unsigned s = p + 1u + c; s < s1; s++) sedge[s] = sv;
    }
}

// ---------------- ATOMIC-FREE scatter: slot = poff[c] + 1 + rank[e] ----------------
__global__ void k_scatter(const int* __restrict__ row, const int* __restrict__ col,
                          const float* __restrict__ ew, const float* __restrict__ dis,
                          const unsigned* __restrict__ poff, const unsigned* __restrict__ rank,
                          int2* __restrict__ sedge, int E){
    int e = blockIdx.x * blockDim.x + threadIdx.x;
    if (e < E){
        int r = row[e], c = col[e];
        float nw = dis[r] * ew[e] * dis[c];
        unsigned p = poff[c] + 1u + rank[e];
        sedge[p] = make_int2(r, __float_as_int(nw));
    }
}

// ---------------- layer-1 fused linear+max-agg via MFMA ----------------
__global__ __launch_bounds__(256) void k_agg1m(const float* __restrict__ xp,
                                               const unsigned short* __restrict__ W1f,
                                               const unsigned* __restrict__ cnt,
                                               const unsigned* __restrict__ poff,
                                               const int2* __restrict__ sedge,
                                               const float* __restrict__ bias,
                                               float* __restrict__ out, int N, int nwaves){
    int wid  = blockIdx.x * 4 + (threadIdx.x >> 6);
    int lane = threadIdx.x & 63;
    int lm   = lane & 31;

    bf16x8 bh[8], bl[8];
    #pragma unroll
    for (int j = 0; j < 8; j++){
        bh[j] = *(const bf16x8*)(W1f + ((size_t)(0 * 8 + j) * 64 + lane) * 8);
        bl[j] = *(const bf16x8*)(W1f + ((size_t)(1 * 8 + j) * 64 + lane) * 8);
    }
    float bv[8];
    #pragma unroll
    for (int j = 0; j < 8; j++){
        int c = 32 * j + lm;
        bv[j] = (c < HID) ? bias[c] : 0.0f;
    }
    const f32x16 zv = {};

    for (int d = wid; d < N; d += nwaves){
        unsigned base = poff[d];
        unsigned nch  = (cnt[d] + 32u) >> 5;
        float m[8];
        #pragma unroll
        for (int j = 0; j < 8; j++) m[j] = -FLT_MAX;

        for (unsigned c = 0; c < nch; c++){
            u16x8 ahu = (u16x8)0, alu = (u16x8)0;
            if (lane < 32){
                int2 e = sedge[base + 32u * c + (unsigned)lm];
                float w = __int_as_float(e.y);
                const float4* xr = (const float4*)(xp + (size_t)e.x * 8);
                float4 x0 = xr[0], x1 = xr[1];
                float p[5] = {w * x0.x, w * x0.y, w * x0.z, w * x0.w, w * x1.x};
                #pragma unroll
                for (int k = 0; k < 5; k++){
                    unsigned short h = f2b_rne(p[k]);
                    ahu[k] = h;
                    alu[k] = f2b_rne(p[k] - b2f(h));
                }
            }
            bf16x8 ah = __builtin_bit_cast(bf16x8, ahu);
            bf16x8 al = __builtin_bit_cast(bf16x8, alu);
            #pragma unroll
            for (int j = 0; j < 8; j += 2){
                f32x16 a0 = __builtin_amdgcn_mfma_f32_32x32x16_bf16(ah, bh[j],     zv, 0, 0, 0);
                f32x16 a1 = __builtin_amdgcn_mfma_f32_32x32x16_bf16(ah, bh[j + 1], zv, 0, 0, 0);
                a0 = __builtin_amdgcn_mfma_f32_32x32x16_bf16(ah, bl[j],     a0, 0, 0, 0);
                a1 = __builtin_amdgcn_mfma_f32_32x32x16_bf16(ah, bl[j + 1], a1, 0, 0, 0);
                a0 = __builtin_amdgcn_mfma_f32_32x32x16_bf16(al, bh[j],     a0, 0, 0, 0);
                a1 = __builtin_amdgcn_mfma_f32_32x32x16_bf16(al, bh[j + 1], a1, 0, 0, 0);
                #pragma unroll
                for (int r = 0; r < 16; r++){
                    m[j]     = fmaxf(m[j],     a0[r]);
                    m[j + 1] = fmaxf(m[j + 1], a1[r]);
                }
            }
        }
        float o[8];
        #pragma unroll
        for (int j = 0; j < 8; j++){
            float other = __shfl_xor(m[j], 32, 64);
            o[j] = fmaxf(fmaxf(m[j], other) + bv[j], 0.0f);
        }
        if (lane < 32){
            float* orow = out + (size_t)d * HID;
            #pragma unroll
            for (int j = 0; j < 8; j++){
                int c = 32 * j + lm;
                if (c < HID) orow[c] = o[j];
            }
        }
    }
}

// ---------------- split-bf16 MFMA GEMM: C = A(M x 240) @ W(240 x Ncol) ----------------
template <bool OB16>
__global__ __launch_bounds__(256) void k_gemm_mfma(const float* __restrict__ A,
                                                   const unsigned short* __restrict__ Bth,
                                                   const unsigned short* __restrict__ Btl,
                                                   const float* __restrict__ bias,
                                                   void* __restrict__ Cv,
                                                   int M, int Ncol, int Npad){
    __shared__ unsigned short As_hi[32][24];
    __shared__ unsigned short As_lo[32][24];
    const int K = 240;
    int t = threadIdx.x;
    int wave = t >> 6, lane = t & 63;
    int m0 = blockIdx.x * 32;
    int n0 = wave * 64;
    bool wact = n0 < Npad;

    int lm   = lane & 31;
    int quad = lane >> 5;

    f32x16 acc0 = {};
    f32x16 acc1 = {};

    for (int k0 = 0; k0 < K; k0 += 16){
        if (t < 128){
            int m = t >> 2, kq = (t & 3) * 4;
            float4 av = make_float4(0.f, 0.f, 0.f, 0.f);
            if (m0 + m < M) av = *(const float4*)(A + (size_t)(m0 + m) * K + k0 + kq);
            ushort4 hi, lo;
            hi.x = f2b_rne(av.x); lo.x = f2b_rne(av.x - b2f(hi.x));
            hi.y = f2b_rne(av.y); lo.y = f2b_rne(av.y - b2f(hi.y));
            hi.z = f2b_rne(av.z); lo.z = f2b_rne(av.z - b2f(hi.z));
            hi.w = f2b_rne(av.w); lo.w = f2b_rne(av.w - b2f(hi.w));
            *(ushort4*)&As_hi[m][kq] = hi;
            *(ushort4*)&As_lo[m][kq] = lo;
        }
        __syncthreads();
        if (wact){
            bf16x8 ah = *(const bf16x8*)&As_hi[lm][quad * 8];
            bf16x8 al = *(const bf16x8*)&As_lo[lm][quad * 8];
            size_t bo0 = (size_t)(n0 + lm) * K + k0 + quad * 8;
            size_t bo1 = (size_t)(n0 + 32 + lm) * K + k0 + quad * 8;
            bf16x8 bh0 = *(const bf16x8*)(Bth + bo0);
            bf16x8 bl0 = *(const bf16x8*)(Btl + bo0);
            bf16x8 bh1 = *(const bf16x8*)(Bth + bo1);
            bf16x8 bl1 = *(const bf16x8*)(Btl + bo1);
            acc0 = __builtin_amdgcn_mfma_f32_32x32x16_bf16(ah, bh0, acc0, 0, 0, 0);
            acc0 = __builtin_amdgcn_mfma_f32_32x32x16_bf16(ah, bl0, acc0, 0, 0, 0);
            acc0 = __builtin_amdgcn_mfma_f32_32x32x16_bf16(al, bh0, acc0, 0, 0, 0);
            acc1 = __builtin_amdgcn_mfma_f32_32x32x16_bf16(ah, bh1, acc1, 0, 0, 0);
            acc1 = __builtin_amdgcn_mfma_f32_32x32x16_bf16(ah, bl1, acc1, 0, 0, 0);
            acc1 = __builtin_amdgcn_mfma_f32_32x32x16_bf16(al, bh1, acc1, 0, 0, 0);
        }
        __syncthreads();
    }

    if (!wact) return;
    #pragma unroll
    for (int h = 0; h < 2; h++){
        int n = n0 + 32 * h + lm;
        if (n >= Ncol) continue;
        float bvv = (!OB16 && bias) ? bias[n] : 0.0f;
        #pragma unroll
        for (int r = 0; r < 16; r++){
            int m = m0 + (r & 3) + 8 * (r >> 2) + 4 * quad;
            if (m >= M) continue;
            float v = (h == 0) ? acc0[r] : acc1[r];
            if (OB16){
                ((unsigned short*)Cv)[(size_t)m * Ncol + n] = f2b_rne(v);
            } else {
                ((float*)Cv)[(size_t)m * Ncol + n] = v + bvv;
            }
        }
    }
}

// ---------------- layer-2 scatter-max over bf16 rows (self slot included), +bias, ReLU ----------------
__global__ __launch_bounds__(256) void k_aggb(const unsigned short* __restrict__ H2,
                                              const unsigned* __restrict__ cnt,
                                              const unsigned* __restrict__ poff,
                                              const int2* __restrict__ sedge,
                                              const float* __restrict__ bias,
                                              float* __restrict__ out, int N){
    int d    = blockIdx.x * 4 + (threadIdx.x >> 6);
    int lane = threadIdx.x & 63;
    if (d >= N) return;
    bool act = lane < 60;

    float4 m = make_float4(-FLT_MAX, -FLT_MAX, -FLT_MAX, -FLT_MAX);
    unsigned p0 = poff[d], p1 = p0 + 1u + cnt[d];
    unsigned p = p0;
    for (; p + 4 <= p1; p += 4){
        int2 e0 = sedge[p], e1 = sedge[p+1], e2 = sedge[p+2], e3 = sedge[p+3];
        if (act){
            ushort4 g0 = ((const ushort4*)(H2 + (size_t)e0.x * HID))[lane];
            ushort4 g1 = ((const ushort4*)(H2 + (size_t)e1.x * HID))[lane];
            ushort4 g2 = ((const ushort4*)(H2 + (size_t)e2.x * HID))[lane];
            ushort4 g3 = ((const ushort4*)(H2 + (size_t)e3.x * HID))[lane];
            float w0 = __int_as_float(e0.y), w1 = __int_as_float(e1.y);
            float w2 = __int_as_float(e2.y), w3 = __int_as_float(e3.y);
            m.x = fmaxf(fmaxf(m.x, w0*b2f(g0.x)), fmaxf(w1*b2f(g1.x), fmaxf(w2*b2f(g2.x), w3*b2f(g3.x))));
            m.y = fmaxf(fmaxf(m.y, w0*b2f(g0.y)), fmaxf(w1*b2f(g1.y), fmaxf(w2*b2f(g2.y), w3*b2f(g3.y))));
            m.z = fmaxf(fmaxf(m.z, w0*b2f(g0.z)), fmaxf(w1*b2f(g1.z), fmaxf(w2*b2f(g2.z), w3*b2f(g3.z))));
            m.w = fmaxf(fmaxf(m.w, w0*b2f(g0.w)), fmaxf(w1*b2f(g1.w), fmaxf(w2*b2f(g2.w), w3*b2f(g3.w))));
        }
    }
    for (; p < p1; p++){
        int2 e0 = sedge[p];
        if (act){
            ushort4 g0 = ((const ushort4*)(H2 + (size_t)e0.x * HID))[lane];
            float w0 = __int_as_float(e0.y);
            m.x = fmaxf(m.x, w0 * b2f(g0.x)); m.y = fmaxf(m.y, w0 * b2f(g0.y));
            m.z = fmaxf(m.z, w0 * b2f(g0.z)); m.w = fmaxf(m.w, w0 * b2f(g0.w));
        }
    }
    if (act){
        float4 b = ((const float4*)bias)[lane];
        float4 o;
        o.x = fmaxf(m.x + b.x, 0.0f);
        o.y = fmaxf(m.y + b.y, 0.0f);
        o.z = fmaxf(m.z + b.z, 0.0f);
        o.w = fmaxf(m.w + b.w, 0.0f);
        ((float4*)(out + (size_t)d * HID))[lane] = o;
    }
}

extern "C" void kernel_launch(void* const* d_in, const int* in_sizes, int n_in,
                              void* d_out, int out_size, void* d_ws, size_t ws_size,
                              hipStream_t stream){
    const float* x  = (const float*)d_in[0];
    const int*   ei = (const int*)  d_in[1];
    const float* ew = (const float*)d_in[2];
    const float* W1 = (const float*)d_in[3];
    const float* b1 = (const float*)d_in[4];
    const float* W2 = (const float*)d_in[5];
    const float* b2 = (const float*)d_in[6];
    const float* We = (const float*)d_in[7];
    const float* be = (const float*)d_in[8];
    float* out = (float*)d_out;

    const int N = in_sizes[0] / 5;
    const int E = in_sizes[2];
    const int* row = ei;
    const int* col = ei + E;
    const int nb = (N + 255) / 256;

    char* w = (char*)d_ws;
    size_t o = 0;
    auto alloc = [&](size_t bytes) -> void* {
        void* p = w + o;
        o = alignUp(o + bytes, 256);
        return p;
    };
    unsigned long long* pk = (unsigned long long*) alloc((size_t)N * 8);
    float*          dis   = (float*)          alloc((size_t)N * 4);
    unsigned*       cnt   = (unsigned*)       alloc((size_t)N * 4);
    unsigned*       poff  = (unsigned*)       alloc((size_t)(N + 1) * 4);
    unsigned*       bsum  = (unsigned*)       alloc((size_t)nb * 4);
    unsigned*       boff  = (unsigned*)       alloc((size_t)nb * 4);
    unsigned*       rank  = (unsigned*)       alloc((size_t)E * 4);
    int2*           sedge = (int2*)           alloc(((size_t)E + 32u * N + 64u) * 8);
    float*          xp    = (float*)          alloc((size_t)N * 8 * 4);
    unsigned short* W1f   = (unsigned short*) alloc((size_t)2 * 8 * 64 * 8 * 2);
    unsigned short* Bt2h  = (unsigned short*) alloc((size_t)256 * HID * 2);
    unsigned short* Bt2l  = (unsigned short*) alloc((size_t)256 * HID * 2);
    unsigned short* Bt3h  = (unsigned short*) alloc((size_t)128 * HID * 2);
    unsigned short* Bt3l  = (unsigned short*) alloc((size_t)128 * HID * 2);
    unsigned short* bufH2 = (unsigned short*) alloc((size_t)N * HID * 2);
    float*          bufB  = (float*)          alloc((size_t)N * HID * 4);
    (void)ws_size; (void)n_in; (void)out_size;

    int be_ = (E + 255) / 256;

    // graph build + weight prep (launch shapes sized per phase — see r11 post-mortem)
    hipMemsetAsync(pk, 0, (size_t)N * 8, stream);
    k_deg_hist <<<be_, 256, 0, stream>>>(col, ew, pk, rank, E);
    k_dis_prep <<<nb + nb + 32 + 240 + 120, 256, 0, stream>>>(pk, dis, cnt, bsum, N, nb,
                                                              x, xp, W1, W1f,
                                                              W2, Bt2h, Bt2l,
                                                              We, Bt3h, Bt3l);
    k_bscan    <<<1, 256, 0, stream>>>(bsum, boff, poff, nb, N);
    k_offs_fill<<<nb, 256, 0, stream>>>(cnt, boff, dis, poff, sedge, N);
    k_scatter  <<<be_, 256, 0, stream>>>(row, col, ew, dis, poff, rank, sedge, E);

    // layer 1: MFMA fused linear + max-agg + b1 + ReLU (1536 blocks = 6144 waves, ~8 dests/wave)
    const int a1blocks = 1536;
    k_agg1m<<<a1blocks, 256, 0, stream>>>(xp, W1f, cnt, poff, sedge, b1, bufB, N, a1blocks * 4);

    // layer 2: split-bf16 MFMA GEMM -> bf16 rows, then bf16-gather max-agg + b2 + ReLU
    int gm = (N + 31) / 32;
    k_gemm_mfma<true><<<gm, 256, 0, stream>>>(bufB, Bt2h, Bt2l, nullptr, bufH2, N, HID, 256);
    k_aggb<<<(N + 3) / 4, 256, 0, stream>>>(bufH2, cnt, poff, sedge, b2, bufB, N);

    // readout: split-bf16 MFMA GEMM -> fp32 out + be
    k_gemm_mfma<false><<<gm, 256, 0, stream>>>(bufB, Bt3h, Bt3l, be, out, N, 80, 128);
}

// Round 13
// 497.186 us; speedup vs baseline: 1.5844x; 1.0305x over previous
//
#include <hip/hip_runtime.h>
#include <cfloat>

#define HID 240

static inline size_t alignUp(size_t x, size_t a){ return (x + a - 1) / a * a; }

typedef __bf16 bf16x8 __attribute__((ext_vector_type(8)));
typedef unsigned short u16x8 __attribute__((ext_vector_type(8)));
typedef float  f32x16 __attribute__((ext_vector_type(16)));

__device__ __forceinline__ float b2f(unsigned short u){
    return __uint_as_float(((unsigned)u) << 16);
}
__device__ __forceinline__ unsigned short f2b_rne(float f){
    unsigned r = __float_as_uint(f);
    r += 0x7FFFu + ((r >> 16) & 1u);
    return (unsigned short)(r >> 16);
}

// ---------------- deg_hist (atomic, full grid) + independent prep on extra blocks ----------------
// blocks [0,ne): edge histogram (packed 64-bit atomic, rank = old cnt)
// blocks [ne,ne+nb): xp pad | then 32 W1f | 240 W2 split | 120 We split
__global__ void k_deg_prep(const int* __restrict__ col, const float* __restrict__ ew,
                           unsigned long long* __restrict__ pk, unsigned* __restrict__ rank,
                           int E, int ne, int N, int nb,
                           const float* __restrict__ x, float* __restrict__ xp,
                           const float* __restrict__ W1, unsigned short* __restrict__ W1f,
                           const float* __restrict__ W2, unsigned short* __restrict__ Bt2h,
                           unsigned short* __restrict__ Bt2l,
                           const float* __restrict__ We, unsigned short* __restrict__ Bt3h,
                           unsigned short* __restrict__ Bt3l){
    int b = blockIdx.x;
    int t = threadIdx.x;
    if (b < ne){
        int e = b * 256 + t;
        if (e < E){
            int c = col[e];
            unsigned q = __float2uint_rn(ew[e] * 1048576.0f);
            unsigned long long old = atomicAdd(&pk[c], (1ull << 40) | (unsigned long long)q);
            rank[e] = (unsigned)(old >> 40);
        }
        return;
    }
    int bb = b - ne;
    if (bb < nb){
        __shared__ float s[1280];
        int rbase = bb * 256;
        #pragma unroll
        for (int c = 0; c < 5; c++){
            int idx = rbase * 5 + t + 256 * c;
            s[t + 256 * c] = (idx < N * 5) ? x[idx] : 0.0f;
        }
        __syncthreads();
        #pragma unroll
        for (int c = 0; c < 8; c++){
            int pos = t + 256 * c;
            int r = pos >> 3, j = pos & 7;
            int grow = rbase + r;
            if (grow < N)
                xp[(size_t)grow * 8 + j] = (j < 5) ? s[r * 5 + j] : 0.0f;
        }
        return;
    }
    bb -= nb;
    if (bb < 32){
        int i = bb * 256 + t;
        if (i < 2 * 8 * 64 * 8){
            int k    = i & 7;
            int lane = (i >> 3) & 63;
            int j    = (i >> 9) & 7;
            int s2   = i >> 12;
            int lm = lane & 31, quad = lane >> 5;
            int kg = quad * 8 + k;
            int colm = 32 * j + lm;
            float v = (kg < 5 && colm < HID) ? W1[kg * HID + colm] : 0.0f;
            unsigned short hi = f2b_rne(v);
            W1f[i] = (s2 == 0) ? hi : f2b_rne(v - b2f(hi));
        }
        return;
    }
    bb -= 32;
    if (bb < 240){
        int i = bb * 256 + t;
        int n = i / HID, k = i - n * HID;
        float v = (n < HID) ? W2[(size_t)k * HID + n] : 0.0f;
        unsigned short hi = f2b_rne(v);
        Bt2h[i] = hi;
        Bt2l[i] = f2b_rne(v - b2f(hi));
        return;
    }
    bb -= 240;
    {
        int i = bb * 256 + t;
        if (i < 128 * HID){
            int n = i / HID, k = i - n * HID;
            float v = (n < 80) ? We[(size_t)k * 80 + n] : 0.0f;
            unsigned short hi = f2b_rne(v);
            Bt3h[i] = hi;
            Bt3l[i] = f2b_rne(v - b2f(hi));
        }
    }
}

// ---------------- unpack pk -> dis,cnt + per-block chunk sums ----------------
__global__ void k_dis_bsum(const unsigned long long* __restrict__ pk,
                           float* __restrict__ dis, unsigned* __restrict__ cnt,
                           unsigned* __restrict__ bsum, int N){
    int b = blockIdx.x;
    int i = b * 256 + threadIdx.x;
    unsigned v = 0u;
    if (i < N){
        unsigned long long p = pk[i];
        unsigned c = (unsigned)(p >> 40);
        cnt[i] = c;
        float deg = 1.0f + (float)(p & 0xFFFFFFFFFFull) * (1.0f / 1048576.0f);
        dis[i] = rsqrtf(deg);
        v = (c + 32u) >> 5;
    }
    #pragma unroll
    for (int o = 32; o > 0; o >>= 1) v += __shfl_down(v, (unsigned)o, 64);
    __shared__ unsigned ws[4];
    int lane = threadIdx.x & 63, w = threadIdx.x >> 6;
    if (lane == 0) ws[w] = v;
    __syncthreads();
    if (threadIdx.x == 0) bsum[b] = ws[0] + ws[1] + ws[2] + ws[3];
}

// ---------------- scan of block sums (nb <= 256); also writes poff[N] ----------------
__global__ void k_bscan(const unsigned* __restrict__ bsum, unsigned* __restrict__ boff,
                        unsigned* __restrict__ poff, int nb, int N){
    __shared__ unsigned s[256];
    int t = threadIdx.x;
    unsigned v = (t < nb) ? bsum[t] : 0u;
    s[t] = v;
    __syncthreads();
    for (int o = 1; o < 256; o <<= 1){
        unsigned u = (t >= o) ? s[t - o] : 0u;
        __syncthreads();
        s[t] += u;
        __syncthreads();
    }
    if (t < nb) boff[t] = s[t] - v;
    if (t == 0) poff[N] = 32u * s[nb - 1];
}

// ---------------- offsets + self-slot/tail fill ----------------
__global__ void k_offs_fill(const unsigned* __restrict__ cnt, const unsigned* __restrict__ boff,
                            const float* __restrict__ dis,
                            unsigned* __restrict__ poff, int2* __restrict__ sedge, int N){
    int b = blockIdx.x, t = threadIdx.x;
    int i = b * 256 + t;
    unsigned c = (i < N) ? cnt[i] : 0u;
    unsigned v = (i < N) ? ((c + 32u) >> 5) : 0u;
    int lane = t & 63, w = t >> 6;
    unsigned x = v;
    #pragma unroll
    for (int o = 1; o < 64; o <<= 1){
        unsigned u = __shfl_up(x, (unsigned)o, 64);
        if (lane >= o) x += u;
    }
    __shared__ unsigned ws[4];
    if (lane == 63) ws[w] = x;
    __syncthreads();
    unsigned wb = 0;
    if (w > 0) wb += ws[0];
    if (w > 1) wb += ws[1];
    if (w > 2) wb += ws[2];
    if (i < N){
        unsigned p = 32u * (boff[b] + wb + x - v);
        poff[i] = p;
        float dd = dis[i];
        int2 sv = make_int2(i, __float_as_int(dd * dd));
        sedge[p] = sv;
        unsigned s1 = p + 32u * v;
        for (unsigned s = p + 1u + c; s < s1; s++) sedge[s] = sv;
    }
}

// ---------------- ATOMIC-FREE scatter: slot = poff[c] + 1 + rank[e] ----------------
__global__ void k_scatter(const int* __restrict__ row, const int* __restrict__ col,
                          const float* __restrict__ ew, const float* __restrict__ dis,
                          const unsigned* __restrict__ poff, const unsigned* __restrict__ rank,
                          int2* __restrict__ sedge, int E){
    int e = blockIdx.x * blockDim.x + threadIdx.x;
    if (e < E){
        int r = row[e], c = col[e];
        float nw = dis[r] * ew[e] * dis[c];
        unsigned p = poff[c] + 1u + rank[e];
        sedge[p] = make_int2(r, __float_as_int(nw));
    }
}

// ---------------- layer-1 fused linear+max-agg via MFMA ----------------
__global__ __launch_bounds__(256) void k_agg1m(const float* __restrict__ xp,
                                               const unsigned short* __restrict__ W1f,
                                               const unsigned* __restrict__ cnt,
                                               const unsigned* __restrict__ poff,
                                               const int2* __restrict__ sedge,
                                               const float* __restrict__ bias,
                                               float* __restrict__ out, int N, int nwaves){
    int wid  = blockIdx.x * 4 + (threadIdx.x >> 6);
    int lane = threadIdx.x & 63;
    int lm   = lane & 31;

    bf16x8 bh[8], bl[8];
    #pragma unroll
    for (int j = 0; j < 8; j++){
        bh[j] = *(const bf16x8*)(W1f + ((size_t)(0 * 8 + j) * 64 + lane) * 8);
        bl[j] = *(const bf16x8*)(W1f + ((size_t)(1 * 8 + j) * 64 + lane) * 8);
    }
    float bv[8];
    #pragma unroll
    for (int j = 0; j < 8; j++){
        int c = 32 * j + lm;
        bv[j] = (c < HID) ? bias[c] : 0.0f;
    }
    const f32x16 zv = {};

    for (int d = wid; d < N; d += nwaves){
        unsigned base = poff[d];
        unsigned nch  = (cnt[d] + 32u) >> 5;
        float m[8];
        #pragma unroll
        for (int j = 0; j < 8; j++) m[j] = -FLT_MAX;

        for (unsigned c = 0; c < nch; c++){
            u16x8 ahu = (u16x8)0, alu = (u16x8)0;
            if (lane < 32){
                int2 e = sedge[base + 32u * c + (unsigned)lm];
                float w = __int_as_float(e.y);
                const float4* xr = (const float4*)(xp + (size_t)e.x * 8);
                float4 x0 = xr[0], x1 = xr[1];
                float p[5] = {w * x0.x, w * x0.y, w * x0.z, w * x0.w, w * x1.x};
                #pragma unroll
                for (int k = 0; k < 5; k++){
                    unsigned short h = f2b_rne(p[k]);
                    ahu[k] = h;
                    alu[k] = f2b_rne(p[k] - b2f(h));
                }
            }
            bf16x8 ah = __builtin_bit_cast(bf16x8, ahu);
            bf16x8 al = __builtin_bit_cast(bf16x8, alu);
            #pragma unroll
            for (int j = 0; j < 8; j += 2){
                f32x16 a0 = __builtin_amdgcn_mfma_f32_32x32x16_bf16(ah, bh[j],     zv, 0, 0, 0);
                f32x16 a1 = __builtin_amdgcn_mfma_f32_32x32x16_bf16(ah, bh[j + 1], zv, 0, 0, 0);
                a0 = __builtin_amdgcn_mfma_f32_32x32x16_bf16(ah, bl[j],     a0, 0, 0, 0);
                a1 = __builtin_amdgcn_mfma_f32_32x32x16_bf16(ah, bl[j + 1], a1, 0, 0, 0);
                a0 = __builtin_amdgcn_mfma_f32_32x32x16_bf16(al, bh[j],     a0, 0, 0, 0);
                a1 = __builtin_amdgcn_mfma_f32_32x32x16_bf16(al, bh[j + 1], a1, 0, 0, 0);
                #pragma unroll
                for (int r = 0; r < 16; r++){
                    m[j]     = fmaxf(m[j],     a0[r]);
                    m[j + 1] = fmaxf(m[j + 1], a1[r]);
                }
            }
        }
        float o[8];
        #pragma unroll
        for (int j = 0; j < 8; j++){
            float other = __shfl_xor(m[j], 32, 64);
            o[j] = fmaxf(fmaxf(m[j], other) + bv[j], 0.0f);
        }
        if (lane < 32){
            float* orow = out + (size_t)d * HID;
            #pragma unroll
            for (int j = 0; j < 8; j++){
                int c = 32 * j + lm;
                if (c < HID) orow[c] = o[j];
            }
        }
    }
}

// ---------------- split-bf16 MFMA GEMM, 64-row tiles: C = A(M x 240) @ W(240 x Ncol) ----------------
// Block: 64m x 256n, 4 waves; wave w covers n [64w,64w+64) x both 32-row halves.
template <bool OB16>
__global__ __launch_bounds__(256) void k_gemm_mfma(const float* __restrict__ A,
                                                   const unsigned short* __restrict__ Bth,
                                                   const unsigned short* __restrict__ Btl,
                                                   const float* __restrict__ bias,
                                                   void* __restrict__ Cv,
                                                   int M, int Ncol, int Npad){
    __shared__ unsigned short As_hi[64][24];
    __shared__ unsigned short As_lo[64][24];
    const int K = 240;
    int t = threadIdx.x;
    int wave = t >> 6, lane = t & 63;
    int m0 = blockIdx.x * 64;
    int n0 = wave * 64;
    bool wact = n0 < Npad;

    int lm   = lane & 31;
    int quad = lane >> 5;

    f32x16 acc[2][2] = {};   // [m-half][n-tile]

    for (int k0 = 0; k0 < K; k0 += 16){
        {
            int m = t >> 2, kq = (t & 3) * 4;   // 64 rows x 4 cols of float4
            float4 av = make_float4(0.f, 0.f, 0.f, 0.f);
            if (m0 + m < M) av = *(const float4*)(A + (size_t)(m0 + m) * K + k0 + kq);
            ushort4 hi, lo;
            hi.x = f2b_rne(av.x); lo.x = f2b_rne(av.x - b2f(hi.x));
            hi.y = f2b_rne(av.y); lo.y = f2b_rne(av.y - b2f(hi.y));
            hi.z = f2b_rne(av.z); lo.z = f2b_rne(av.z - b2f(hi.z));
            hi.w = f2b_rne(av.w); lo.w = f2b_rne(av.w - b2f(hi.w));
            *(ushort4*)&As_hi[m][kq] = hi;
            *(ushort4*)&As_lo[m][kq] = lo;
        }
        __syncthreads();
        if (wact){
            size_t bo0 = (size_t)(n0 + lm) * K + k0 + quad * 8;
            size_t bo1 = (size_t)(n0 + 32 + lm) * K + k0 + quad * 8;
            bf16x8 bh0 = *(const bf16x8*)(Bth + bo0);
            bf16x8 bl0 = *(const bf16x8*)(Btl + bo0);
            bf16x8 bh1 = *(const bf16x8*)(Bth + bo1);
            bf16x8 bl1 = *(const bf16x8*)(Btl + bo1);
            #pragma unroll
            for (int mh = 0; mh < 2; mh++){
                bf16x8 ah = *(const bf16x8*)&As_hi[32 * mh + lm][quad * 8];
                bf16x8 al = *(const bf16x8*)&As_lo[32 * mh + lm][quad * 8];
                acc[mh][0] = __builtin_amdgcn_mfma_f32_32x32x16_bf16(ah, bh0, acc[mh][0], 0, 0, 0);
                acc[mh][0] = __builtin_amdgcn_mfma_f32_32x32x16_bf16(ah, bl0, acc[mh][0], 0, 0, 0);
                acc[mh][0] = __builtin_amdgcn_mfma_f32_32x32x16_bf16(al, bh0, acc[mh][0], 0, 0, 0);
                acc[mh][1] = __builtin_amdgcn_mfma_f32_32x32x16_bf16(ah, bh1, acc[mh][1], 0, 0, 0);
                acc[mh][1] = __builtin_amdgcn_mfma_f32_32x32x16_bf16(ah, bl1, acc[mh][1], 0, 0, 0);
                acc[mh][1] = __builtin_amdgcn_mfma_f32_32x32x16_bf16(al, bh1, acc[mh][1], 0, 0, 0);
            }
        }
        __syncthreads();
    }

    if (!wact) return;
    #pragma unroll
    for (int mh = 0; mh < 2; mh++){
        #pragma unroll
        for (int h = 0; h < 2; h++){
            int n = n0 + 32 * h + lm;
            if (n >= Ncol) continue;
            float bvv = (!OB16 && bias) ? bias[n] : 0.0f;
            #pragma unroll
            for (int r = 0; r < 16; r++){
                int m = m0 + 32 * mh + (r & 3) + 8 * (r >> 2) + 4 * quad;
                if (m >= M) continue;
                float v = acc[mh][h][r];
                if (OB16){
                    ((unsigned short*)Cv)[(size_t)m * Ncol + n] = f2b_rne(v);
                } else {
                    ((float*)Cv)[(size_t)m * Ncol + n] = v + bvv;
                }
            }
        }
    }
}

// ---------------- layer-2 scatter-max over bf16 rows (self slot included), +bias, ReLU ----------------
__global__ __launch_bounds__(256) void k_aggb(const unsigned short* __restrict__ H2,
                                              const unsigned* __restrict__ cnt,
                                              const unsigned* __restrict__ poff,
                                              const int2* __restrict__ sedge,
                                              const float* __restrict__ bias,
                                              float* __restrict__ out, int N){
    int d    = blockIdx.x * 4 + (threadIdx.x >> 6);
    int lane = threadIdx.x & 63;
    if (d >= N) return;
    bool act = lane < 60;

    float4 m = make_float4(-FLT_MAX, -FLT_MAX, -FLT_MAX, -FLT_MAX);
    unsigned p0 = poff[d], p1 = p0 + 1u + cnt[d];
    unsigned p = p0;
    for (; p + 4 <= p1; p += 4){
        int2 e0 = sedge[p], e1 = sedge[p+1], e2 = sedge[p+2], e3 = sedge[p+3];
        if (act){
            ushort4 g0 = ((const ushort4*)(H2 + (size_t)e0.x * HID))[lane];
            ushort4 g1 = ((const ushort4*)(H2 + (size_t)e1.x * HID))[lane];
            ushort4 g2 = ((const ushort4*)(H2 + (size_t)e2.x * HID))[lane];
            ushort4 g3 = ((const ushort4*)(H2 + (size_t)e3.x * HID))[lane];
            float w0 = __int_as_float(e0.y), w1 = __int_as_float(e1.y);
            float w2 = __int_as_float(e2.y), w3 = __int_as_float(e3.y);
            m.x = fmaxf(fmaxf(m.x, w0*b2f(g0.x)), fmaxf(w1*b2f(g1.x), fmaxf(w2*b2f(g2.x), w3*b2f(g3.x))));
            m.y = fmaxf(fmaxf(m.y, w0*b2f(g0.y)), fmaxf(w1*b2f(g1.y), fmaxf(w2*b2f(g2.y), w3*b2f(g3.y))));
            m.z = fmaxf(fmaxf(m.z, w0*b2f(g0.z)), fmaxf(w1*b2f(g1.z), fmaxf(w2*b2f(g2.z), w3*b2f(g3.z))));
            m.w = fmaxf(fmaxf(m.w, w0*b2f(g0.w)), fmaxf(w1*b2f(g1.w), fmaxf(w2*b2f(g2.w), w3*b2f(g3.w))));
        }
    }
    for (; p < p1; p++){
        int2 e0 = sedge[p];
        if (act){
            ushort4 g0 = ((const ushort4*)(H2 + (size_t)e0.x * HID))[lane];
            float w0 = __int_as_float(e0.y);
            m.x = fmaxf(m.x, w0 * b2f(g0.x)); m.y = fmaxf(m.y, w0 * b2f(g0.y));
            m.z = fmaxf(m.z, w0 * b2f(g0.z)); m.w = fmaxf(m.w, w0 * b2f(g0.w));
        }
    }
    if (act){
        float4 b = ((const float4*)bias)[lane];
        float4 o;
        o.x = fmaxf(m.x + b.x, 0.0f);
        o.y = fmaxf(m.y + b.y, 0.0f);
        o.z = fmaxf(m.z + b.z, 0.0f);
        o.w = fmaxf(m.w + b.w, 0.0f);
        ((float4*)(out + (size_t)d * HID))[lane] = o;
    }
}

extern "C" void kernel_launch(void* const* d_in, const int* in_sizes, int n_in,
                              void* d_out, int out_size, void* d_ws, size_t ws_size,
                              hipStream_t stream){
    const float* x  = (const float*)d_in[0];
    const int*   ei = (const int*)  d_in[1];
    const float* ew = (const float*)d_in[2];
    const float* W1 = (const float*)d_in[3];
    const float* b1 = (const float*)d_in[4];
    const float* W2 = (const float*)d_in[5];
    const float* b2 = (const float*)d_in[6];
    const float* We = (const float*)d_in[7];
    const float* be = (const float*)d_in[8];
    float* out = (float*)d_out;

    const int N = in_sizes[0] / 5;
    const int E = in_sizes[2];
    const int* row = ei;
    const int* col = ei + E;
    const int nb = (N + 255) / 256;

    char* w = (char*)d_ws;
    size_t o = 0;
    auto alloc = [&](size_t bytes) -> void* {
        void* p = w + o;
        o = alignUp(o + bytes, 256);
        return p;
    };
    unsigned long long* pk = (unsigned long long*) alloc((size_t)N * 8);
    float*          dis   = (float*)          alloc((size_t)N * 4);
    unsigned*       cnt   = (unsigned*)       alloc((size_t)N * 4);
    unsigned*       poff  = (unsigned*)       alloc((size_t)(N + 1) * 4);
    unsigned*       bsum  = (unsigned*)       alloc((size_t)nb * 4);
    unsigned*       boff  = (unsigned*)       alloc((size_t)nb * 4);
    unsigned*       rank  = (unsigned*)       alloc((size_t)E * 4);
    int2*           sedge = (int2*)           alloc(((size_t)E + 32u * N + 64u) * 8);
    float*          xp    = (float*)          alloc((size_t)N * 8 * 4);
    unsigned short* W1f   = (unsigned short*) alloc((size_t)2 * 8 * 64 * 8 * 2);
    unsigned short* Bt2h  = (unsigned short*) alloc((size_t)256 * HID * 2);
    unsigned short* Bt2l  = (unsigned short*) alloc((size_t)256 * HID * 2);
    unsigned short* Bt3h  = (unsigned short*) alloc((size_t)128 * HID * 2);
    unsigned short* Bt3l  = (unsigned short*) alloc((size_t)128 * HID * 2);
    unsigned short* bufH2 = (unsigned short*) alloc((size_t)N * HID * 2);
    float*          bufB  = (float*)          alloc((size_t)N * HID * 4);
    (void)ws_size; (void)n_in; (void)out_size;

    int ne = (E + 255) / 256;

    // graph build; independent weight/x prep rides the atomic-bound launch for free
    hipMemsetAsync(pk, 0, (size_t)N * 8, stream);
    k_deg_prep <<<ne + nb + 32 + 240 + 120, 256, 0, stream>>>(col, ew, pk, rank, E, ne, N, nb,
                                                              x, xp, W1, W1f,
                                                              W2, Bt2h, Bt2l,
                                                              We, Bt3h, Bt3l);
    k_dis_bsum <<<nb, 256, 0, stream>>>(pk, dis, cnt, bsum, N);
    k_bscan    <<<1, 256, 0, stream>>>(bsum, boff, poff, nb, N);
    k_offs_fill<<<nb, 256, 0, stream>>>(cnt, boff, dis, poff, sedge, N);
    k_scatter  <<<ne, 256, 0, stream>>>(row, col, ew, dis, poff, rank, sedge, E);

    // layer 1: MFMA fused linear + max-agg + b1 + ReLU
    const int a1blocks = 1536;
    k_agg1m<<<a1blocks, 256, 0, stream>>>(xp, W1f, cnt, poff, sedge, b1, bufB, N, a1blocks * 4);

    // layer 2: split-bf16 MFMA GEMM (64-row tiles) -> bf16 rows, then gather max-agg
    int gm = (N + 63) / 64;
    k_gemm_mfma<true><<<gm, 256, 0, stream>>>(bufB, Bt2h, Bt2l, nullptr, bufH2, N, HID, 256);
    k_aggb<<<(N + 3) / 4, 256, 0, stream>>>(bufH2, cnt, poff, sedge, b2, bufB, N);

    // readout: split-bf16 MFMA GEMM -> fp32 out + be
    k_gemm_mfma<false><<<gm, 256, 0, stream>>>(bufB, Bt3h, Bt3l, be, out, N, 80, 128);
}